// Round 9
// baseline (131.343 us; speedup 1.0000x reference)
//
#include <hip/hip_runtime.h>

// Problem constants: B=2, S=2048, E=1024, H=16, D=64, WIN=16
#define BB 2
#define SS 2048
#define EE 1024
#define HH 16
#define DD 64
#define NY 5120   // merged projection output cols: [Kcls|Vcls|Qloc|Kloc|Vloc]

typedef __attribute__((ext_vector_type(8))) short short8;
typedef __attribute__((ext_vector_type(4))) float f32x4;

__device__ __forceinline__ float bf2f(unsigned short u) {
  union { unsigned int i; float f; } v; v.i = ((unsigned int)u) << 16; return v.f;
}
__device__ __forceinline__ unsigned short f2bf(float f) {
  unsigned int u = __float_as_uint(f);
  u += 0x7fff + ((u >> 16) & 1);   // RNE
  return (unsigned short)(u >> 16);
}
__device__ __forceinline__ void gload_lds16(const void* g, void* l) {
  __builtin_amdgcn_global_load_lds(
      (const __attribute__((address_space(1))) void*)g,
      (__attribute__((address_space(3))) void*)l, 16, 0, 0);
}

// ---------------- fused f32->bf16 casts + q_cls GEMV (one launch) ----------------
__global__ void cast_all(const float* __restrict__ s0, unsigned short* __restrict__ d0,
                         const float* __restrict__ s1, unsigned short* __restrict__ d1,
                         const float* __restrict__ s2, unsigned short* __restrict__ d2,
                         const float* __restrict__ s3, unsigned short* __restrict__ d3,
                         const float* __restrict__ in_w_cls,
                         const float* __restrict__ in_b_cls,
                         float* __restrict__ qcls) {
  int b = blockIdx.x;
  if (b >= 10240) {   // q_cls GEMV: 512 blocks x 4 rows
    int gw = (b - 10240) * 4 + (threadIdx.x >> 6);
    int lane = threadIdx.x & 63;
    int bb = gw >> 10, n = gw & 1023;
    const float* x = s0 + (size_t)bb * SS * EE;
    const float* w = in_w_cls + (size_t)n * EE;
    float s = 0.0f;
    for (int k = lane; k < EE; k += 64) s += x[k] * w[k];
    for (int o = 32; o; o >>= 1) s += __shfl_xor(s, o);
    if (lane == 0) qcls[bb * EE + n] = s + in_b_cls[n];
    return;
  }
  const float* s; unsigned short* d; int idx;
  if (b < 4096)      { s = s0; d = d0; idx = b; }
  else if (b < 6144) { s = s1; d = d1; idx = b - 4096; }
  else if (b < 9216) { s = s2; d = d2; idx = b - 6144; }
  else               { s = s3; d = d3; idx = b - 9216; }
  int i = (idx * 256 + threadIdx.x) * 4;
  float4 v = *reinterpret_cast<const float4*>(s + i);
  ushort4 o;
  o.x = f2bf(v.x); o.y = f2bf(v.y); o.z = f2bf(v.z); o.w = f2bf(v.w);
  *reinterpret_cast<ushort4*>(d + i) = o;
}

// ================= 256x320 projection GEMM — barrier-light pipeline ==============
// Y[4096][5120] = Xbf[4096][1024] @ W[5120][1024]^T + bias
// 512 thr = 8 waves (2M x 4N), per-wave 128x80 (acc 8x5), BK=64, 16 K-tiles.
// Per K-tile: issue 9 global_load_lds for t+1 (buf c^1), then one compiler-scheduled
// compute of buf c (26 ds_read_b128 + 80 MFMA per wave — compiler's fine-grained
// lgkmcnt interleaving overlaps LDS BW under MFMA), then ONE __syncthreads seam
// (its vmcnt(0) is free: staging issued ~2500 cyc earlier). No intra-tile barriers:
// reads hit buf c, staging writes hit c^1 — no hazard. Seam barrier guarantees
// (a) all reads of c^1 from tile t-1 done before staging into it, (b) staging
// visible to all waves before tile t+1 reads it.
__global__ __launch_bounds__(512, 2)
void gemm8p(const unsigned short* __restrict__ Ag,   // [4096][1024]
            const unsigned short* __restrict__ Bg,   // [5120][1024]
            const float* __restrict__ bcls,
            const float* __restrict__ bloc,
            unsigned short* __restrict__ Yout) {     // [4096][5120]
  __shared__ unsigned short As2[2][256][64];   // 64 KiB
  __shared__ unsigned short Bs2[2][320][64];   // 80 KiB
  char* ldsA = (char*)As2;
  char* ldsB = (char*)Bs2;

  const int tid = threadIdx.x;
  const int wid = tid >> 6;
  const int lane = tid & 63;
  const int wm = wid >> 2;     // 0..1 -> 128-row slice
  const int wn = wid & 3;      // 0..3 -> 80-col slice
  const int rl = lane & 15;
  const int g4 = lane >> 4;

  int bid = blockIdx.x;
  bid = (bid & 7) * 32 + (bid >> 3);     // XCD swizzle, bijective (256 = 8*32)
  const int tileM = (bid & 15) * 256;
  const int tileN = (bid >> 4) * 320;

  f32x4 acc[8][5] = {};

  auto SA = [&](int c, int kk, int i) {   // A slab i = rows i*64..i*64+63 (8 KB)
    int flat = i * 8192 + tid * 16;
    int row = flat >> 7;
    int colb = (flat & 127) ^ ((row & 7) << 4);
    gload_lds16(Ag + (size_t)(tileM + row) * 1024 + kk + (colb >> 1),
                ldsA + c * 32768 + i * 8192 + wid * 1024);
  };
  auto SB = [&](int c, int kk, int j) {   // B slab j = rows j*64..j*64+63 (8 KB)
    int flat = j * 8192 + tid * 16;
    int row = flat >> 7;
    int colb = (flat & 127) ^ ((row & 7) << 4);
    gload_lds16(Bg + (size_t)(tileN + row) * 1024 + kk + (colb >> 1),
                ldsB + c * 40960 + j * 8192 + wid * 1024);
  };
  auto STAGE = [&](int c, int kk) {
    SB(c, kk, 0); SB(c, kk, 1); SB(c, kk, 2); SB(c, kk, 3); SB(c, kk, 4);
    SA(c, kk, 0); SA(c, kk, 1); SA(c, kk, 2); SA(c, kk, 3);
  };

  // prologue: tile 0 -> buf0
  STAGE(0, 0);
  __syncthreads();

#pragma unroll 1
  for (int t = 0; t < 16; ++t) {
    const int c = t & 1;
    if (t < 15) STAGE(c ^ 1, (t + 1) * 64);   // flies under this tile's compute

    // compute tile t from buf c — compiler-scheduled ds_read/MFMA interleave
#pragma unroll
    for (int kh = 0; kh < 2; ++kh) {
      short8 bfr[5];
#pragma unroll
      for (int n = 0; n < 5; ++n) {
        int row = wn * 80 + n * 16 + rl;
        const char* base = ldsB + c * 40960 + row * 128;
        bfr[n] = *(const short8*)(base + ((kh * 64 + g4 * 16) ^ ((row & 7) << 4)));
      }
#pragma unroll
      for (int mh = 0; mh < 2; ++mh) {
        short8 afr[4];
#pragma unroll
        for (int m = 0; m < 4; ++m) {
          int row = wm * 128 + mh * 64 + m * 16 + rl;
          const char* base = ldsA + c * 32768 + row * 128;
          afr[m] = *(const short8*)(base + ((kh * 64 + g4 * 16) ^ ((row & 7) << 4)));
        }
#pragma unroll
        for (int m = 0; m < 4; ++m)
#pragma unroll
          for (int n = 0; n < 5; ++n)
            acc[mh * 4 + m][n] = __builtin_amdgcn_mfma_f32_16x16x32_bf16(
                bfr[n], afr[m], acc[mh * 4 + m][n], 0, 0, 0);
      }
    }
    __syncthreads();   // seam: drains vmcnt (staging landed long ago) + syncs waves
  }

  // epilogue (swapped layout): lane holds 4 consecutive cols ->
  // row = tileM + wm*128 + m*16 + rl ; col = tileN + wn*80 + n*16 + g4*4 + r
  float4 bv4[5];
#pragma unroll
  for (int n = 0; n < 5; ++n) {
    int gc = tileN + wn * 80 + n * 16 + g4 * 4;
    bv4[n] = *(const float4*)((gc < 2048) ? &bcls[1024 + gc] : &bloc[gc - 2048]);
  }
#pragma unroll
  for (int m = 0; m < 8; ++m) {
    int gr = tileM + wm * 128 + m * 16 + rl;
    unsigned short* yrow = Yout + (size_t)gr * NY + tileN + wn * 80 + g4 * 4;
#pragma unroll
    for (int n = 0; n < 5; ++n) {
      ushort4 o;
      o.x = f2bf(acc[m][n][0] + bv4[n].x);
      o.y = f2bf(acc[m][n][1] + bv4[n].y);
      o.z = f2bf(acc[m][n][2] + bv4[n].z);
      o.w = f2bf(acc[m][n][3] + bv4[n].w);
      *(ushort4*)(yrow + n * 16) = o;
    }
  }
}

// ---------------- 128x128 2-phase GEMM (out-proj only) ----------------
template <int OUT_BF16>
__global__ __launch_bounds__(256, 4)
void gemm_bt(const unsigned short* __restrict__ A,
             const unsigned short* __restrict__ B,
             const float* __restrict__ bias0,
             void* __restrict__ C, int M, int N, int K) {
  __shared__ unsigned short As[2][128 * 32];
  __shared__ unsigned short Bs[2][128 * 32];
  const int tid = threadIdx.x;
  const int wid = tid >> 6;
  const int lane = tid & 63;

  const int nx = gridDim.x;
  int bid = blockIdx.y * nx + blockIdx.x;
  const int nwg = nx * gridDim.y;
  if ((nwg & 7) == 0) { int c = nwg >> 3; bid = (bid & 7) * c + (bid >> 3); }
  const int tileM = (bid % nx) * 128;
  const int tileN = (bid / nx) * 128;

  const int wm = (wid >> 1) * 64;
  const int wn = (wid & 1) * 64;
  const int rl = lane & 15;
  const int kc = (lane >> 4) * 8;

  f32x4 acc[4][4] = {};

  const int srow = tid >> 2;
  const int scol = (tid & 3) * 8;
  const unsigned short* gA = A + (size_t)(tileM + srow) * K + scol;
  const unsigned short* gB = B + (size_t)(tileN + srow) * K + scol;
  char* lA = (char*)As + wid * 1024;
  char* lB = (char*)Bs + wid * 1024;

  auto STAGE = [&](int buf, int k0) {
    gload_lds16(gA + k0, lA + buf * 8192);
    gload_lds16(gA + (size_t)64 * K + k0, lA + buf * 8192 + 4096);
    gload_lds16(gB + k0, lB + buf * 8192);
    gload_lds16(gB + (size_t)64 * K + k0, lB + buf * 8192 + 4096);
  };
  auto COMPUTE = [&](int buf) {
    const unsigned short* as = As[buf];
    const unsigned short* bs = Bs[buf];
    short8 af[4], bfg[4];
#pragma unroll
    for (int mi = 0; mi < 4; ++mi)
      af[mi] = *reinterpret_cast<const short8*>(&as[(wm + mi * 16 + rl) * 32 + kc]);
#pragma unroll
    for (int ni = 0; ni < 4; ++ni)
      bfg[ni] = *reinterpret_cast<const short8*>(&bs[(wn + ni * 16 + rl) * 32 + kc]);
#pragma unroll
    for (int mi = 0; mi < 4; ++mi)
#pragma unroll
      for (int ni = 0; ni < 4; ++ni)
        acc[mi][ni] = __builtin_amdgcn_mfma_f32_16x16x32_bf16(
            af[mi], bfg[ni], acc[mi][ni], 0, 0, 0);
  };

  STAGE(0, 0);
  asm volatile("s_waitcnt vmcnt(0)" ::: "memory");
  __syncthreads();
  int cur = 0;
  for (int k0 = 32; k0 < K; k0 += 32) {
    STAGE(cur ^ 1, k0);
    COMPUTE(cur);
    asm volatile("s_waitcnt vmcnt(0)" ::: "memory");
    __syncthreads();
    cur ^= 1;
  }
  COMPUTE(cur);

  const int crow0 = (lane >> 4) * 4;
  const int ccol = lane & 15;
#pragma unroll
  for (int mi = 0; mi < 4; ++mi)
#pragma unroll
    for (int ni = 0; ni < 4; ++ni) {
      int gc = tileN + wn + ni * 16 + ccol;
      float bv = bias0[gc];
#pragma unroll
      for (int r = 0; r < 4; ++r) {
        int gr = tileM + wm + mi * 16 + crow0 + r;
        if (gr < M) {
          float v = acc[mi][ni][r] + bv;
          if (OUT_BF16)
            ((unsigned short*)C)[(size_t)gr * N + gc] = f2bf(v);
          else
            ((float*)C)[(size_t)gr * N + gc] = v;
        }
      }
    }
}

// ---------------- fused attention: local (x<16) + global partials (x>=16) ----------------
#define QBL 128
#define VT_PAD 168
#define P_PAD 72
__global__ __launch_bounds__(256, 2)
void attn_fused(const float* __restrict__ qcls,
                const unsigned short* __restrict__ Y,
                float* __restrict__ part,
                unsigned short* __restrict__ CTX) {
  const int h = blockIdx.y, b = blockIdx.z;
  const int tid = threadIdx.x, wid = tid >> 6, lane = tid & 63;

  __shared__ unsigned short Vt[64][VT_PAD];
  __shared__ unsigned short Pl[4][32][P_PAD];
  __shared__ float qf[64];
  __shared__ float ps[256];
  __shared__ float red[8];
  __shared__ float pacc[4][64];

  if (blockIdx.x >= 16) {
    // ===== global (cls) attention partial, key-chunk kc =====
    const int kc = blockIdx.x - 16;
    if (tid < 64) qf[tid] = qcls[b * EE + h * DD + tid];
    __syncthreads();

    int s = kc * 256 + tid;
    const short8* k8 = (const short8*)(Y + (size_t)(b * SS + s) * NY + h * DD);
    float dot = 0.0f;
#pragma unroll
    for (int i = 0; i < 8; ++i) {
      short8 kv = k8[i];
#pragma unroll
      for (int e = 0; e < 8; ++e) dot += qf[i * 8 + e] * bf2f((unsigned short)kv[e]);
    }
    dot *= 0.125f;

    float mx = dot;
    for (int o = 32; o; o >>= 1) mx = fmaxf(mx, __shfl_xor(mx, o));
    if ((tid & 63) == 0) red[tid >> 6] = mx;
    __syncthreads();
    float M = fmaxf(fmaxf(red[0], red[1]), fmaxf(red[2], red[3]));

    float p = __expf(dot - M);
    ps[tid] = p;
    float l = p;
    for (int o = 32; o; o >>= 1) l += __shfl_xor(l, o);
    if ((tid & 63) == 0) red[4 + (tid >> 6)] = l;
    __syncthreads();
    float L = red[4] + red[5] + red[6] + red[7];

    int g = tid >> 6, d = tid & 63;
    float acc = 0.0f;
    for (int sl = g; sl < 256; sl += 4)
      acc += ps[sl] * bf2f(Y[(size_t)(b * SS + kc * 256 + sl) * NY + 1024 + h * DD + d]);
    pacc[g][d] = acc;
    __syncthreads();
    if (g == 0) {
      float a = pacc[0][d] + pacc[1][d] + pacc[2][d] + pacc[3][d];
      float* pp = part + ((size_t)(b * HH + h) * 8 + kc) * 66;
      if (d == 0) { pp[0] = M; pp[1] = L; }
      pp[2 + d] = a;
    }
    return;
  }

  // ===== local attention via MFMA =====
  const int s0 = blockIdx.x * QBL;
  const int rl = lane & 15, g = lane >> 4;

  for (int task = tid; task < 640; task += 256) {
    int kp = task % 80, ch = task / 80;
    int k0 = kp * 2;
    int kg0 = min(max(s0 - 16 + k0, 0), SS - 1);
    int kg1 = min(max(s0 - 16 + k0 + 1, 0), SS - 1);
    short8 a = *(const short8*)&Y[(size_t)(b * SS + kg0) * NY + 4096 + h * DD + ch * 8];
    short8 bv = *(const short8*)&Y[(size_t)(b * SS + kg1) * NY + 4096 + h * DD + ch * 8];
#pragma unroll
    for (int e = 0; e < 8; ++e) {
      unsigned int w = (unsigned int)(unsigned short)a[e] |
                       ((unsigned int)(unsigned short)bv[e] << 16);
      *(unsigned int*)&Vt[ch * 8 + e][k0] = w;
    }
  }
  __syncthreads();

  const int qb = s0 + wid * 32;
  const int kb = qb - 16;

  short8 ak[4][2];
#pragma unroll
  for (int kt = 0; kt < 4; ++kt) {
    int kg = min(max(kb + kt * 16 + rl, 0), SS - 1);
    const unsigned short* kr = &Y[(size_t)(b * SS + kg) * NY + 3072 + h * DD + g * 8];
#pragma unroll
    for (int ks = 0; ks < 2; ++ks) ak[kt][ks] = *(const short8*)(kr + ks * 32);
  }
  short8 bq[2][2];
#pragma unroll
  for (int cc = 0; cc < 2; ++cc) {
    const unsigned short* qr = &Y[(size_t)(b * SS + qb + cc * 16 + rl) * NY + 2048 + h * DD + g * 8];
#pragma unroll
    for (int ks = 0; ks < 2; ++ks) bq[cc][ks] = *(const short8*)(qr + ks * 32);
  }

  f32x4 accs[4][2] = {};
#pragma unroll
  for (int kt = 0; kt < 4; ++kt)
#pragma unroll
    for (int cc = 0; cc < 2; ++cc)
#pragma unroll
      for (int ks = 0; ks < 2; ++ks)
        accs[kt][cc] = __builtin_amdgcn_mfma_f32_16x16x32_bf16(
            ak[kt][ks], bq[cc][ks], accs[kt][cc], 0, 0, 0);

  float mrow[2] = {-3e38f, -3e38f};
#pragma unroll
  for (int kt = 0; kt < 4; ++kt)
#pragma unroll
    for (int cc = 0; cc < 2; ++cc)
#pragma unroll
      for (int r = 0; r < 4; ++r) {
        int kg = kb + kt * 16 + 4 * g + r;
        int qg = qb + cc * 16 + rl;
        bool valid = (kg >= qg - 16) && (kg <= qg + 16) && (kg >= 1) && (kg < SS);
        float v = valid ? accs[kt][cc][r] : -3e38f;
        accs[kt][cc][r] = v;
        mrow[cc] = fmaxf(mrow[cc], v);
      }
#pragma unroll
  for (int cc = 0; cc < 2; ++cc) {
    float m = mrow[cc];
    m = fmaxf(m, __shfl_xor(m, 16));
    m = fmaxf(m, __shfl_xor(m, 32));
    mrow[cc] = m;
  }

  float zrow[2] = {0.0f, 0.0f};
#pragma unroll
  for (int cc = 0; cc < 2; ++cc)
#pragma unroll
    for (int kt = 0; kt < 4; ++kt) {
      ushort4 pw;
#pragma unroll
      for (int r = 0; r < 4; ++r) {
        float p = __expf((accs[kt][cc][r] - mrow[cc]) * 0.125f);
        zrow[cc] += p;
        ((unsigned short*)&pw)[r] = f2bf(p);
      }
      *(ushort4*)&Pl[wid][cc * 16 + rl][kt * 16 + 4 * g] = pw;
    }
#pragma unroll
  for (int cc = 0; cc < 2; ++cc) {
    float z = zrow[cc];
    z += __shfl_xor(z, 16);
    z += __shfl_xor(z, 32);
    zrow[cc] = 1.0f / z;
  }

  f32x4 accp[4][2] = {};
#pragma unroll
  for (int ks = 0; ks < 2; ++ks) {
    short8 bp[2];
#pragma unroll
    for (int cc = 0; cc < 2; ++cc)
      bp[cc] = *(const short8*)&Pl[wid][cc * 16 + rl][ks * 32 + g * 8];
#pragma unroll
    for (int mt = 0; mt < 4; ++mt) {
      short8 av = *(const short8*)&Vt[mt * 16 + rl][wid * 32 + ks * 32 + g * 8];
#pragma unroll
      for (int cc = 0; cc < 2; ++cc)
        accp[mt][cc] = __builtin_amdgcn_mfma_f32_16x16x32_bf16(
            av, bp[cc], accp[mt][cc], 0, 0, 0);
    }
  }

#pragma unroll
  for (int mt = 0; mt < 4; ++mt)
#pragma unroll
    for (int cc = 0; cc < 2; ++cc) {
      int token = qb + cc * 16 + rl;
      if (token == 0) {
        *(ushort4*)&CTX[(size_t)(b * SS) * EE + h * DD + mt * 16 + 4 * g] = ushort4{0, 0, 0, 0};
        continue;
      }
      ushort4 o;
#pragma unroll
      for (int r = 0; r < 4; ++r)
        ((unsigned short*)&o)[r] = f2bf(accp[mt][cc][r] * zrow[cc]);
      *(ushort4*)&CTX[(size_t)(b * SS + token) * EE + h * DD + mt * 16 + 4 * g] = o;
    }
}

// ---------------- cls output rows: combine partials + GEMV (one launch) ----------------
__global__ void gemv_cls(const float* __restrict__ part,
                         const float* __restrict__ Wc,     // out_w_cls [1024][1024]
                         const float* __restrict__ bc,
                         float* __restrict__ out) {
  __shared__ float ctx[EE];
  __shared__ float u[HH][8];
  const int b = blockIdx.x >> 8;
  const int tid = threadIdx.x;
  const float* pb = part + (size_t)b * HH * 8 * 66;
  if (tid < HH) {
    const float* pp = pb + tid * 8 * 66;
    float M = -1e30f;
#pragma unroll
    for (int i = 0; i < 8; ++i) M = fmaxf(M, pp[i * 66]);
    float Z = 0.0f, w[8];
#pragma unroll
    for (int i = 0; i < 8; ++i) { w[i] = __expf(pp[i * 66] - M); Z += w[i] * pp[i * 66 + 1]; }
#pragma unroll
    for (int i = 0; i < 8; ++i) u[tid][i] = w[i] / Z;
  }
  __syncthreads();
  for (int k = tid; k < EE; k += 256) {
    int hh = k >> 6, d = k & 63;
    const float* pp = pb + hh * 8 * 66 + 2 + d;
    float a = 0.0f;
#pragma unroll
    for (int i = 0; i < 8; ++i) a += u[hh][i] * pp[i * 66];
    ctx[k] = a;
  }
  __syncthreads();
  int n = (blockIdx.x & 255) * 4 + (tid >> 6);
  int lane = tid & 63;
  const float* w = Wc + (size_t)n * EE;
  float s = 0.0f;
  for (int k = lane; k < EE; k += 64) s += ctx[k] * w[k];
  for (int o = 32; o; o >>= 1) s += __shfl_xor(s, o);
  if (lane == 0) out[(size_t)b * SS * EE + n] = s + bc[n];
}

extern "C" void kernel_launch(void* const* d_in, const int* in_sizes, int n_in,
                              void* d_out, int out_size, void* d_ws, size_t ws_size,
                              hipStream_t stream) {
  const float* hs        = (const float*)d_in[0];
  const float* in_w_cls  = (const float*)d_in[1];
  const float* in_b_cls  = (const float*)d_in[2];
  const float* out_w_cls = (const float*)d_in[3];
  const float* out_b_cls = (const float*)d_in[4];
  const float* in_w_loc  = (const float*)d_in[5];
  const float* in_b_loc  = (const float*)d_in[6];
  const float* out_w_loc = (const float*)d_in[7];
  const float* out_b_loc = (const float*)d_in[8];
  float* out = (float*)d_out;

  const int M = BB * SS;  // 4096
  char* ws = (char*)d_ws;
  size_t off = 0;
  auto alloc = [&](size_t bytes) { char* p = ws + off; off += (bytes + 255) & ~(size_t)255; return p; };
  unsigned short* Xbf  = (unsigned short*)alloc((size_t)M * EE * 2);
  unsigned short* W    = (unsigned short*)alloc((size_t)NY * EE * 2);
  unsigned short* Wout = (unsigned short*)alloc((size_t)EE * EE * 2);
  unsigned short* Yb   = (unsigned short*)alloc((size_t)M * NY * 2);
  unsigned short* CTX  = (unsigned short*)alloc((size_t)M * EE * 2);
  float* qcls = (float*)alloc(2 * EE * 4);
  float* part = (float*)alloc((size_t)BB * HH * 8 * 66 * 4);

  // 1) fused casts + q_cls GEMV
  cast_all<<<10752, 256, 0, stream>>>(
      hs, Xbf,
      in_w_cls + (size_t)EE * EE, W,
      in_w_loc, W + (size_t)2048 * EE,
      out_w_loc, Wout,
      in_w_cls, in_b_cls, qcls);

  // 2) merged projection GEMM (barrier-light, 256x320 tiles, 256 blocks)
  gemm8p<<<256, 512, 0, stream>>>(Xbf, W, in_b_cls, in_b_loc, Yb);

  // 3) fused attention (local MFMA + cls partials)
  attn_fused<<<dim3(24, HH, BB), 256, 0, stream>>>(qcls, Yb, part, CTX);

  // 4) local output projection (writes all rows of d_out; rows 0,2048 fixed next)
  {
    dim3 g3(M / 128, EE / 128);
    gemm_bt<0><<<g3, 256, 0, stream>>>(CTX, Wout, out_b_loc, out, M, EE, EE);
  }

  // 5) cls output rows (combine + GEMV fused)
  gemv_cls<<<512, 256, 0, stream>>>(part, out_w_cls, out_b_cls, out);
}